// Round 1
// baseline (1206.448 us; speedup 1.0000x reference)
//
#include <hip/hip_runtime.h>

#pragma clang fp contract(off)

#define N_ANCH 321408
#define KSEL 4096
#define POST 300
#define EQCAP 4096

typedef unsigned int u32;
typedef unsigned long long u64;

// ---------------- scoring: key = float bits of sigmoid(max logit), 0 if below thr ----
__global__ void k_keys(const float* __restrict__ cls, u32* __restrict__ keys) {
    int i = blockIdx.x * blockDim.x + threadIdx.x;
    if (i >= N_ANCH) return;
    float c0 = cls[3 * i], c1 = cls[3 * i + 1], c2 = cls[3 * i + 2];
    float m = fmaxf(c0, fmaxf(c1, c2));
    float s = 1.0f / (1.0f + expf(-m));
    keys[i] = (s >= 0.05f) ? __float_as_uint(s) : 0u;
}

__global__ void k_hist1(const u32* __restrict__ keys, u32* __restrict__ hist) {
    int i = blockIdx.x * blockDim.x + threadIdx.x;
    if (i >= N_ANCH) return;
    atomicAdd(&hist[keys[i] >> 16], 1u);
}

__global__ void k_hist2(const u32* __restrict__ keys, u32* __restrict__ hist2,
                        const u32* __restrict__ scal) {
    int i = blockIdx.x * blockDim.x + threadIdx.x;
    if (i >= N_ANCH) return;
    u32 k = keys[i];
    if ((k >> 16) == scal[0]) atomicAdd(&hist2[k & 0xFFFFu], 1u);
}

// single block, 1024 threads; finds crossing bucket from the top
__global__ __launch_bounds__(1024) void k_scan(const u32* __restrict__ hist, u32* scal, int pass) {
    __shared__ u32 sh[1024];
    int t = threadIdx.x;
    int hi = 65535 - t * 64;
    u32 s = 0;
    for (int j = 0; j < 64; ++j) s += hist[hi - j];
    sh[t] = s;
    __syncthreads();
    for (int off = 1; off < 1024; off <<= 1) {
        u32 x = sh[t];
        u32 y = (t >= off) ? sh[t - off] : 0u;
        __syncthreads();
        sh[t] = x + y;
        __syncthreads();
    }
    u32 incl = sh[t];
    u32 excl = incl - s;
    u32 base = (pass == 2) ? scal[1] : 0u;
    u32 target = 4096u - base;
    if (excl < target && excl + s >= target) {
        u32 cum = excl;
        for (int j = 0; j < 64; ++j) {
            int b = hi - j;
            u32 c = hist[b];
            if (cum + c >= target) {
                if (pass == 1) { scal[0] = (u32)b; scal[1] = cum; }
                else {
                    u32 T = (scal[0] << 16) | (u32)b;
                    u32 cgt = base + cum;
                    scal[2] = T; scal[3] = cgt; scal[4] = 4096u - cgt;
                }
                break;
            }
            cum += c;
        }
    }
}

__global__ void k_compact(const u32* __restrict__ keys, u32* scal, u64* __restrict__ sel,
                          u32* __restrict__ eq) {
    int i = blockIdx.x * blockDim.x + threadIdx.x;
    if (i >= N_ANCH) return;
    u32 k = keys[i];
    u32 T = scal[2];
    if (k > T) {
        u32 p = atomicAdd(&scal[5], 1u);
        sel[p] = (((u64)k) << 32) | (u32)(~(u32)i);
    } else if (k == T) {
        u32 p = atomicAdd(&scal[6], 1u);
        if (p < EQCAP) eq[p] = (u32)i;
    }
}

// sort the ==T indices ascending, append first keq of them
__global__ __launch_bounds__(512) void k_eqfill(const u32* __restrict__ scal,
                                                const u32* __restrict__ eq, u64* __restrict__ sel) {
    __shared__ u32 a[EQCAP];
    int t = threadIdx.x;
    u32 ce = scal[6]; if (ce > EQCAP) ce = EQCAP;
    u32 keq = scal[4], cgt = scal[3], T = scal[2];
    for (int i = t; i < EQCAP; i += 512) a[i] = (i < (int)ce) ? eq[i] : 0xFFFFFFFFu;
    __syncthreads();
    for (u32 k2 = 2; k2 <= EQCAP; k2 <<= 1)
        for (u32 j = k2 >> 1; j > 0; j >>= 1) {
            for (u32 i = t; i < EQCAP; i += 512) {
                u32 ixj = i ^ j;
                if (ixj > i) {
                    u32 x = a[i], y = a[ixj];
                    bool up = ((i & k2) == 0);
                    if ((x > y) == up) { a[i] = y; a[ixj] = x; }
                }
            }
            __syncthreads();
        }
    for (u32 jj = t; jj < keq; jj += 512)
        sel[cgt + jj] = (jj < ce) ? ((((u64)T) << 32) | (u32)(~a[jj])) : 0ULL;
}

// bitonic sort 4096 u64 descending: (scorebits<<32)|~idx  => score desc, idx asc
__global__ __launch_bounds__(512) void k_sortsel(u64* __restrict__ sel) {
    __shared__ u64 a[KSEL];
    int t = threadIdx.x;
    for (int i = t; i < KSEL; i += 512) a[i] = sel[i];
    __syncthreads();
    for (u32 k2 = 2; k2 <= (u32)KSEL; k2 <<= 1)
        for (u32 j = k2 >> 1; j > 0; j >>= 1) {
            for (u32 i = t; i < (u32)KSEL; i += 512) {
                u32 ixj = i ^ j;
                if (ixj > i) {
                    u64 x = a[i], y = a[ixj];
                    bool up = ((i & k2) == 0);
                    if ((x < y) == up) { a[i] = y; a[ixj] = x; }  // descending
                }
            }
            __syncthreads();
        }
    for (int i = t; i < KSEL; i += 512) sel[i] = a[i];
}

__global__ void k_decode(const u64* __restrict__ sel, const float* __restrict__ boxp,
                         const float* __restrict__ anch, float* __restrict__ boxes7,
                         float4* __restrict__ bb, float* __restrict__ area,
                         float* __restrict__ prescore, u32* __restrict__ preidx) {
    int r = blockIdx.x * blockDim.x + threadIdx.x;
    if (r >= KSEL) return;
    u64 c = sel[r];
    u32 key = (u32)(c >> 32);
    u32 idx = ~((u32)(c & 0xFFFFFFFFull));
    if (key == 0u) idx = 0u;
    const float* a7 = anch + (size_t)idx * 7;
    const float* t7 = boxp + (size_t)idx * 7;
    float xa = a7[0], ya = a7[1], za = a7[2], wa = a7[3], la = a7[4], ha = a7[5], ra = a7[6];
    float xt = t7[0], yt = t7[1], zt = t7[2], wt = t7[3], lt_ = t7[4], ht = t7[5], rt = t7[6];
    za = za + ha * 0.5f;
    float diag = sqrtf(la * la + wa * wa);
    float xg = xt * diag + xa;
    float yg = yt * diag + ya;
    float zg = zt * ha + za;
    float lg = expf(lt_) * la;
    float wg = expf(wt) * wa;
    float hg = expf(ht) * ha;
    float rg = rt + ra;
    zg = zg - hg * 0.5f;
    float* b = boxes7 + (size_t)r * 7;
    b[0] = xg; b[1] = yg; b[2] = zg; b[3] = wg; b[4] = lg; b[5] = hg; b[6] = rg;
    // standup from (x,y,w,l,r): px = cx*c + cy*s ; py = cx*(-s) + cy*c
    float cc = cosf(rg), ss = sinf(rg);
    float dx = wg * 0.5f, dy = lg * 0.5f;
    const float sxs[4] = {-1.f, -1.f, 1.f, 1.f};
    const float sys[4] = {-1.f, 1.f, 1.f, -1.f};
    float minx = 1e30f, miny = 1e30f, maxx = -1e30f, maxy = -1e30f;
    for (int k = 0; k < 4; ++k) {
        float cx = dx * sxs[k], cy = dy * sys[k];
        float px = cx * cc + cy * ss;
        float py = cx * (-ss) + cy * cc;
        px = px + xg; py = py + yg;
        minx = fminf(minx, px); maxx = fmaxf(maxx, px);
        miny = fminf(miny, py); maxy = fmaxf(maxy, py);
    }
    bb[r] = make_float4(minx, miny, maxx, maxy);
    area[r] = (maxx - minx) * (maxy - miny);
    prescore[r] = (key == 0u) ? -1.0f : __uint_as_float(key);
    preidx[r] = idx;
}

__global__ __launch_bounds__(64) void k_mask(const float4* __restrict__ bb,
                                             const float* __restrict__ area,
                                             u64* __restrict__ mask) {
    int i = blockIdx.y * 64 + threadIdx.x;
    int cb = blockIdx.x;
    __shared__ float4 ob[64];
    __shared__ float oa[64];
    int jg0 = cb * 64;
    ob[threadIdx.x] = bb[jg0 + threadIdx.x];
    oa[threadIdx.x] = area[jg0 + threadIdx.x];
    __syncthreads();
    float4 m = bb[i];
    float ma = area[i];
    u64 bits = 0;
    for (int j = 0; j < 64; ++j) {
        int jg = jg0 + j;
        if (jg == i) continue;
        float4 o = ob[j];
        float ltx = fmaxf(m.x, o.x), lty = fmaxf(m.y, o.y);
        float rbx = fminf(m.z, o.z), rby = fminf(m.w, o.w);
        float w = fmaxf(rbx - ltx, 0.0f), h = fmaxf(rby - lty, 0.0f);
        float inter = w * h;
        float iou = inter / (ma + oa[j] - inter + 1e-8f);
        if (iou > 0.5f) bits |= (1ULL << j);
    }
    mask[(size_t)i * 64 + cb] = bits;
}

// one wave; lane l owns suppression word l (64 bits each -> 4096 boxes)
__global__ __launch_bounds__(64) void k_serial(const u64* __restrict__ mask,
                                               const float* __restrict__ prescore,
                                               u32* __restrict__ keep_list, u32* __restrict__ scal) {
    int lane = threadIdx.x;
    u64 vw = 0;
    for (int j = 0; j < 64; ++j)
        if (prescore[(size_t)lane * 64 + j] > 0.0f) vw |= (1ULL << j);
    u64 remv = 0;
    int cnt = 0;
    u64 r0 = mask[(size_t)0 * 64 + lane], r1 = mask[(size_t)1 * 64 + lane];
    u64 r2 = mask[(size_t)2 * 64 + lane], r3 = mask[(size_t)3 * 64 + lane];
    u64 r4 = mask[(size_t)4 * 64 + lane], r5 = mask[(size_t)5 * 64 + lane];
    u64 r6 = mask[(size_t)6 * 64 + lane], r7 = mask[(size_t)7 * 64 + lane];
    for (int i = 0; i < KSEL; ++i) {
        u64 row = r0;
        r0 = r1; r1 = r2; r2 = r3; r3 = r4; r4 = r5; r5 = r6; r6 = r7;
        int nf = i + 8;
        r7 = (nf < KSEL) ? mask[(size_t)nf * 64 + lane] : 0ULL;
        int w = i >> 6, b = i & 63;
        int kw = (int)(((vw >> b) & ~(remv >> b)) & 1ULL);
        int kept = __shfl(kw, w);
        if (kept) {
            remv |= row;
            if (lane == 0 && cnt < POST) keep_list[cnt] = (u32)i;
            cnt++;
        }
    }
    if (lane == 0) scal[7] = (u32)(cnt < POST ? cnt : POST);
}

__global__ void k_final(const u32* __restrict__ scal, const u32* __restrict__ keep_list,
                        const float* __restrict__ boxes7, const float* __restrict__ prescore,
                        const u32* __restrict__ preidx, const float* __restrict__ cls,
                        const float* __restrict__ dirp, float* __restrict__ out) {
    int t = blockIdx.x * blockDim.x + threadIdx.x;
    if (t >= POST) return;
    u32 m = scal[7];
    float* ob = out;
    float* os = out + POST * 7;
    float* ol = os + POST;
    float* ov = ol + POST;
    if (t < (int)m) {
        u32 r = keep_list[t];
        u32 i = preidx[r];
        float b[7];
        for (int q = 0; q < 7; ++q) b[q] = boxes7[(size_t)r * 7 + q];
        float d0 = dirp[(size_t)i * 2], d1 = dirp[(size_t)i * 2 + 1];
        int dl = (d1 > d0) ? 1 : 0;
        int pos = (b[6] > 0.0f) ? 1 : 0;
        if (pos ^ dl) b[6] = b[6] + 3.14159265358979323846f;
        for (int q = 0; q < 7; ++q) ob[(size_t)t * 7 + q] = b[q];
        os[t] = prescore[r];
        float c0 = cls[(size_t)i * 3], c1 = cls[(size_t)i * 3 + 1], c2 = cls[(size_t)i * 3 + 2];
        int lab = 0; float best = c0;
        if (c1 > best) { lab = 1; best = c1; }
        if (c2 > best) { lab = 2; }
        ol[t] = (float)lab;
        ov[t] = 1.0f;
    } else {
        for (int q = 0; q < 7; ++q) ob[(size_t)t * 7 + q] = 0.0f;
        os[t] = 0.0f;
        ol[t] = -1.0f;
        ov[t] = 0.0f;
    }
}

extern "C" void kernel_launch(void* const* d_in, const int* in_sizes, int n_in,
                              void* d_out, int out_size, void* d_ws, size_t ws_size,
                              hipStream_t stream) {
    const float* box_preds = (const float*)d_in[0];
    const float* cls_preds = (const float*)d_in[1];
    const float* dir_preds = (const float*)d_in[2];
    const float* anchors   = (const float*)d_in[3];
    float* out = (float*)d_out;

    unsigned char* w = (unsigned char*)d_ws;
    size_t off = 0;
    auto nxt = [&](size_t bytes) -> void* {
        void* p = (void*)(w + off);
        off = (off + bytes + 255) & ~(size_t)255;
        return p;
    };
    u32* keys      = (u32*)nxt((size_t)N_ANCH * 4);
    u32* hist1     = (u32*)nxt(65536 * 4);
    u32* hist2     = (u32*)nxt(65536 * 4);
    u32* scal      = (u32*)nxt(64 * 4);
    u64* sel       = (u64*)nxt((size_t)KSEL * 8);
    u32* eq        = (u32*)nxt((size_t)EQCAP * 4);
    float* boxes7  = (float*)nxt((size_t)KSEL * 7 * 4);
    float4* bb     = (float4*)nxt((size_t)KSEL * 16);
    float* area    = (float*)nxt((size_t)KSEL * 4);
    float* prescore= (float*)nxt((size_t)KSEL * 4);
    u32* preidx    = (u32*)nxt((size_t)KSEL * 4);
    u64* mask      = (u64*)nxt((size_t)KSEL * 64 * 8);
    u32* keep_list = (u32*)nxt(512 * 4);

    hipMemsetAsync(hist1, 0, 65536 * 4, stream);
    hipMemsetAsync(hist2, 0, 65536 * 4, stream);
    hipMemsetAsync(scal, 0, 64 * 4, stream);

    int blocks = (N_ANCH + 255) / 256;
    k_keys<<<blocks, 256, 0, stream>>>(cls_preds, keys);
    k_hist1<<<blocks, 256, 0, stream>>>(keys, hist1);
    k_scan<<<1, 1024, 0, stream>>>(hist1, scal, 1);
    k_hist2<<<blocks, 256, 0, stream>>>(keys, hist2, scal);
    k_scan<<<1, 1024, 0, stream>>>(hist2, scal, 2);
    k_compact<<<blocks, 256, 0, stream>>>(keys, scal, sel, eq);
    k_eqfill<<<1, 512, 0, stream>>>(scal, eq, sel);
    k_sortsel<<<1, 512, 0, stream>>>(sel);
    k_decode<<<KSEL / 256, 256, 0, stream>>>(sel, box_preds, anchors, boxes7, bb, area, prescore, preidx);
    dim3 mg(64, 64);
    k_mask<<<mg, 64, 0, stream>>>(bb, area, mask);
    k_serial<<<1, 64, 0, stream>>>(mask, prescore, keep_list, scal);
    k_final<<<2, 256, 0, stream>>>(scal, keep_list, boxes7, prescore, preidx, cls_preds, dir_preds, out);
}

// Round 2
// 528.928 us; speedup vs baseline: 2.2809x; 2.2809x over previous
//
#include <hip/hip_runtime.h>

#pragma clang fp contract(off)

#define N_ANCH 321408
#define KSEL 4096
#define POST 300
#define EQCAP 4096

typedef unsigned int u32;
typedef unsigned long long u64;

// ---------------- scoring + pass-1 histogram fused ----------------
__global__ void k_keys(const float* __restrict__ cls, u32* __restrict__ keys,
                       u32* __restrict__ hist) {
    int i = blockIdx.x * blockDim.x + threadIdx.x;
    if (i >= N_ANCH) return;
    float c0 = cls[3 * i], c1 = cls[3 * i + 1], c2 = cls[3 * i + 2];
    float m = fmaxf(c0, fmaxf(c1, c2));
    float s = 1.0f / (1.0f + expf(-m));
    u32 k = (s >= 0.05f) ? __float_as_uint(s) : 0u;
    keys[i] = k;
    atomicAdd(&hist[k >> 16], 1u);
}

__global__ void k_hist2(const u32* __restrict__ keys, u32* __restrict__ hist2,
                        const u32* __restrict__ scal) {
    int i = blockIdx.x * blockDim.x + threadIdx.x;
    if (i >= N_ANCH) return;
    u32 k = keys[i];
    if ((k >> 16) == scal[0]) atomicAdd(&hist2[k & 0xFFFFu], 1u);
}

// single block, 1024 threads; finds crossing bucket from the top
__global__ __launch_bounds__(1024) void k_scan(const u32* __restrict__ hist, u32* scal, int pass) {
    __shared__ u32 sh[1024];
    int t = threadIdx.x;
    int hi = 65535 - t * 64;
    u32 s = 0;
    for (int j = 0; j < 64; ++j) s += hist[hi - j];
    sh[t] = s;
    __syncthreads();
    for (int off = 1; off < 1024; off <<= 1) {
        u32 x = sh[t];
        u32 y = (t >= off) ? sh[t - off] : 0u;
        __syncthreads();
        sh[t] = x + y;
        __syncthreads();
    }
    u32 incl = sh[t];
    u32 excl = incl - s;
    u32 base = (pass == 2) ? scal[1] : 0u;
    u32 target = 4096u - base;
    if (excl < target && excl + s >= target) {
        u32 cum = excl;
        for (int j = 0; j < 64; ++j) {
            int b = hi - j;
            u32 c = hist[b];
            if (cum + c >= target) {
                if (pass == 1) { scal[0] = (u32)b; scal[1] = cum; }
                else {
                    u32 T = (scal[0] << 16) | (u32)b;
                    u32 cgt = base + cum;
                    scal[2] = T; scal[3] = cgt; scal[4] = 4096u - cgt;
                }
                break;
            }
            cum += c;
        }
    }
}

__global__ void k_compact(const u32* __restrict__ keys, u32* scal, u64* __restrict__ sel,
                          u32* __restrict__ eq) {
    int i = blockIdx.x * blockDim.x + threadIdx.x;
    if (i >= N_ANCH) return;
    u32 k = keys[i];
    u32 T = scal[2];
    if (k > T) {
        u32 p = atomicAdd(&scal[5], 1u);
        sel[p] = (((u64)k) << 32) | (u32)(~(u32)i);
    } else if (k == T) {
        u32 p = atomicAdd(&scal[6], 1u);
        if (p < EQCAP) eq[p] = (u32)i;
    }
}

// rank the ==T indices by counting (ascending index); append the keq smallest
__global__ __launch_bounds__(1024) void k_eqrank(const u32* __restrict__ scal,
                                                 const u32* __restrict__ eq,
                                                 u64* __restrict__ sel) {
    __shared__ u32 ch[1024];
    u32 ce = scal[6]; if (ce > EQCAP) ce = EQCAP;
    u32 keq = scal[4], cgt = scal[3], T = scal[2];
    int t = threadIdx.x;
    for (u32 p0 = 0; p0 < ce; p0 += 1024) {
        u32 p = p0 + (u32)t;
        u32 mine = (p < ce) ? eq[p] : 0xFFFFFFFFu;
        u32 rank = 0;
        for (u32 base = 0; base < ce; base += 1024) {
            u32 n = ce - base; if (n > 1024u) n = 1024u;
            __syncthreads();
            if ((u32)t < n) ch[t] = eq[base + t];
            __syncthreads();
            for (u32 j = 0; j < n; ++j) rank += (ch[j] < mine) ? 1u : 0u;
        }
        if (p < ce && rank < keq) sel[cgt + rank] = (((u64)T) << 32) | (u32)(~mine);
    }
}

// rank-by-counting scatter: all 4096 packed keys distinct -> permutation
__global__ __launch_bounds__(256) void k_rank(const u64* __restrict__ sel,
                                              u64* __restrict__ sorted) {
    __shared__ u64 ch[2048];
    int r = blockIdx.x * 256 + threadIdx.x;
    u64 mine = sel[r];
    int rank = 0;
    for (int base = 0; base < KSEL; base += 2048) {
        for (int j = threadIdx.x; j < 2048; j += 256) ch[j] = sel[base + j];
        __syncthreads();
        #pragma unroll 8
        for (int j = 0; j < 2048; ++j) rank += (ch[j] > mine) ? 1 : 0;
        __syncthreads();
    }
    sorted[rank] = mine;   // descending: rank 0 = max key
}

__global__ void k_decode(const u64* __restrict__ sel, const float* __restrict__ boxp,
                         const float* __restrict__ anch, float* __restrict__ boxes7,
                         float4* __restrict__ bb, float* __restrict__ area,
                         float* __restrict__ prescore, u32* __restrict__ preidx) {
    int r = blockIdx.x * blockDim.x + threadIdx.x;
    if (r >= KSEL) return;
    u64 c = sel[r];
    u32 key = (u32)(c >> 32);
    u32 idx = ~((u32)(c & 0xFFFFFFFFull));
    if (key == 0u) idx = 0u;
    const float* a7 = anch + (size_t)idx * 7;
    const float* t7 = boxp + (size_t)idx * 7;
    float xa = a7[0], ya = a7[1], za = a7[2], wa = a7[3], la = a7[4], ha = a7[5], ra = a7[6];
    float xt = t7[0], yt = t7[1], zt = t7[2], wt = t7[3], lt_ = t7[4], ht = t7[5], rt = t7[6];
    za = za + ha * 0.5f;
    float diag = sqrtf(la * la + wa * wa);
    float xg = xt * diag + xa;
    float yg = yt * diag + ya;
    float zg = zt * ha + za;
    float lg = expf(lt_) * la;
    float wg = expf(wt) * wa;
    float hg = expf(ht) * ha;
    float rg = rt + ra;
    zg = zg - hg * 0.5f;
    float* b = boxes7 + (size_t)r * 7;
    b[0] = xg; b[1] = yg; b[2] = zg; b[3] = wg; b[4] = lg; b[5] = hg; b[6] = rg;
    float cc = cosf(rg), ss = sinf(rg);
    float dx = wg * 0.5f, dy = lg * 0.5f;
    const float sxs[4] = {-1.f, -1.f, 1.f, 1.f};
    const float sys[4] = {-1.f, 1.f, 1.f, -1.f};
    float minx = 1e30f, miny = 1e30f, maxx = -1e30f, maxy = -1e30f;
    for (int k = 0; k < 4; ++k) {
        float cx = dx * sxs[k], cy = dy * sys[k];
        float px = cx * cc + cy * ss;
        float py = cx * (-ss) + cy * cc;
        px = px + xg; py = py + yg;
        minx = fminf(minx, px); maxx = fmaxf(maxx, px);
        miny = fminf(miny, py); maxy = fmaxf(maxy, py);
    }
    bb[r] = make_float4(minx, miny, maxx, maxy);
    area[r] = (maxx - minx) * (maxy - miny);
    prescore[r] = (key == 0u) ? -1.0f : __uint_as_float(key);
    preidx[r] = idx;
}

__global__ __launch_bounds__(64) void k_mask(const float4* __restrict__ bb,
                                             const float* __restrict__ area,
                                             u64* __restrict__ mask) {
    int i = blockIdx.y * 64 + threadIdx.x;
    int cb = blockIdx.x;
    __shared__ float4 ob[64];
    __shared__ float oa[64];
    int jg0 = cb * 64;
    ob[threadIdx.x] = bb[jg0 + threadIdx.x];
    oa[threadIdx.x] = area[jg0 + threadIdx.x];
    __syncthreads();
    float4 m = bb[i];
    float ma = area[i];
    u64 bits = 0;
    for (int j = 0; j < 64; ++j) {
        int jg = jg0 + j;
        if (jg == i) continue;
        float4 o = ob[j];
        float ltx = fmaxf(m.x, o.x), lty = fmaxf(m.y, o.y);
        float rbx = fminf(m.z, o.z), rby = fminf(m.w, o.w);
        float w = fmaxf(rbx - ltx, 0.0f), h = fmaxf(rby - lty, 0.0f);
        float inter = w * h;
        float iou = inter / (ma + oa[j] - inter + 1e-8f);
        if (iou > 0.5f) bits |= (1ULL << j);
    }
    mask[(size_t)i * 64 + cb] = bits;
}

__device__ __forceinline__ u64 shfl_u64(u64 v, int src) {
    int lo = __shfl((int)(u32)(v & 0xFFFFFFFFull), src);
    int hi = __shfl((int)(u32)(v >> 32), src);
    return (((u64)(u32)hi) << 32) | (u32)lo;
}

__device__ __forceinline__ int first_avail(u64 avail) {
    u64 ball = __ballot(avail != 0);
    if (ball == 0) return -1;
    int src = (int)__builtin_ctzll(ball);
    u64 w = shfl_u64(avail, src);
    int bit = (int)__builtin_ctzll(w);
    return src * 64 + bit;
}

// one wave; lane l owns bits [l*64, l*64+64) of the availability bitmap.
// Skip-ahead greedy NMS: only kept boxes cost a dependent mask-row fetch;
// 2-deep speculative prefetch of the next candidate's row.
__global__ __launch_bounds__(64) void k_serial(const u64* __restrict__ mask,
                                               const float* __restrict__ prescore,
                                               u32* __restrict__ keep_list, u32* __restrict__ scal) {
    int lane = threadIdx.x;
    u64 avail = 0;
    for (int j = 0; j < 64; ++j)
        if (prescore[(size_t)lane * 64 + j] > 0.0f) avail |= (1ULL << j);
    int cnt = 0;
    int i = first_avail(avail);
    while (i >= 0 && cnt < POST) {
        // second candidate before suppression (speculative)
        u64 tmp = avail;
        if (lane == (i >> 6)) tmp &= ~(1ULL << (i & 63));
        int i2 = first_avail(tmp);
        u64 row = mask[(size_t)i * 64 + lane];
        u64 row2 = (i2 >= 0) ? mask[(size_t)i2 * 64 + lane] : 0ULL;
        if (lane == 0) keep_list[cnt] = (u32)i;
        cnt++;
        avail &= ~row;
        if (lane == (i >> 6)) avail &= ~(1ULL << (i & 63));
        int inext = first_avail(avail);
        if (inext >= 0 && inext == i2 && cnt < POST) {
            if (lane == 0) keep_list[cnt] = (u32)i2;
            cnt++;
            avail &= ~row2;
            if (lane == (i2 >> 6)) avail &= ~(1ULL << (i2 & 63));
            inext = first_avail(avail);
        }
        i = inext;
    }
    if (lane == 0) scal[7] = (u32)cnt;
}

__global__ void k_final(const u32* __restrict__ scal, const u32* __restrict__ keep_list,
                        const float* __restrict__ boxes7, const float* __restrict__ prescore,
                        const u32* __restrict__ preidx, const float* __restrict__ cls,
                        const float* __restrict__ dirp, float* __restrict__ out) {
    int t = blockIdx.x * blockDim.x + threadIdx.x;
    if (t >= POST) return;
    u32 m = scal[7];
    float* ob = out;
    float* os = out + POST * 7;
    float* ol = os + POST;
    float* ov = ol + POST;
    if (t < (int)m) {
        u32 r = keep_list[t];
        u32 i = preidx[r];
        float b[7];
        for (int q = 0; q < 7; ++q) b[q] = boxes7[(size_t)r * 7 + q];
        float d0 = dirp[(size_t)i * 2], d1 = dirp[(size_t)i * 2 + 1];
        int dl = (d1 > d0) ? 1 : 0;
        int pos = (b[6] > 0.0f) ? 1 : 0;
        if (pos ^ dl) b[6] = b[6] + 3.14159265358979323846f;
        for (int q = 0; q < 7; ++q) ob[(size_t)t * 7 + q] = b[q];
        os[t] = prescore[r];
        float c0 = cls[(size_t)i * 3], c1 = cls[(size_t)i * 3 + 1], c2 = cls[(size_t)i * 3 + 2];
        int lab = 0; float best = c0;
        if (c1 > best) { lab = 1; best = c1; }
        if (c2 > best) { lab = 2; }
        ol[t] = (float)lab;
        ov[t] = 1.0f;
    } else {
        for (int q = 0; q < 7; ++q) ob[(size_t)t * 7 + q] = 0.0f;
        os[t] = 0.0f;
        ol[t] = -1.0f;
        ov[t] = 0.0f;
    }
}

extern "C" void kernel_launch(void* const* d_in, const int* in_sizes, int n_in,
                              void* d_out, int out_size, void* d_ws, size_t ws_size,
                              hipStream_t stream) {
    const float* box_preds = (const float*)d_in[0];
    const float* cls_preds = (const float*)d_in[1];
    const float* dir_preds = (const float*)d_in[2];
    const float* anchors   = (const float*)d_in[3];
    float* out = (float*)d_out;

    unsigned char* w = (unsigned char*)d_ws;
    size_t off = 0;
    auto nxt = [&](size_t bytes) -> void* {
        void* p = (void*)(w + off);
        off = (off + bytes + 255) & ~(size_t)255;
        return p;
    };
    u32* keys      = (u32*)nxt((size_t)N_ANCH * 4);
    u32* hist1     = (u32*)nxt(65536 * 4);
    u32* hist2     = (u32*)nxt(65536 * 4);
    u32* scal      = (u32*)nxt(64 * 4);
    u64* sel       = (u64*)nxt((size_t)KSEL * 8);
    u64* sel2      = (u64*)nxt((size_t)KSEL * 8);
    u32* eq        = (u32*)nxt((size_t)EQCAP * 4);
    float* boxes7  = (float*)nxt((size_t)KSEL * 7 * 4);
    float4* bb     = (float4*)nxt((size_t)KSEL * 16);
    float* area    = (float*)nxt((size_t)KSEL * 4);
    float* prescore= (float*)nxt((size_t)KSEL * 4);
    u32* preidx    = (u32*)nxt((size_t)KSEL * 4);
    u64* mask      = (u64*)nxt((size_t)KSEL * 64 * 8);
    u32* keep_list = (u32*)nxt(512 * 4);

    // hist1, hist2, scal are contiguous in ws: one memset covers all three
    hipMemsetAsync(hist1, 0, (size_t)65536 * 4 * 2 + 256, stream);

    int blocks = (N_ANCH + 255) / 256;
    k_keys<<<blocks, 256, 0, stream>>>(cls_preds, keys, hist1);
    k_scan<<<1, 1024, 0, stream>>>(hist1, scal, 1);
    k_hist2<<<blocks, 256, 0, stream>>>(keys, hist2, scal);
    k_scan<<<1, 1024, 0, stream>>>(hist2, scal, 2);
    k_compact<<<blocks, 256, 0, stream>>>(keys, scal, sel, eq);
    k_eqrank<<<1, 1024, 0, stream>>>(scal, eq, sel);
    k_rank<<<KSEL / 256, 256, 0, stream>>>(sel, sel2);
    k_decode<<<KSEL / 256, 256, 0, stream>>>(sel2, box_preds, anchors, boxes7, bb, area, prescore, preidx);
    dim3 mg(64, 64);
    k_mask<<<mg, 64, 0, stream>>>(bb, area, mask);
    k_serial<<<1, 64, 0, stream>>>(mask, prescore, keep_list, scal);
    k_final<<<2, 256, 0, stream>>>(scal, keep_list, boxes7, prescore, preidx, cls_preds, dir_preds, out);
}

// Round 3
// 291.953 us; speedup vs baseline: 4.1323x; 1.8117x over previous
//
#include <hip/hip_runtime.h>

#pragma clang fp contract(off)

#define N_ANCH 321408
#define KSEL 4096
#define POST 300
#define EQCAP 4096
#define H1BINS 1024
#define H1BASE 0x3D40u   // remap: bin = (k>>16) - H1BASE + 1 ; bin 0 = invalid (k==0)

typedef unsigned int u32;
typedef unsigned long long u64;

// ---------------- scoring + pass-1 histogram (LDS-privatized) ----------------
__global__ __launch_bounds__(1024) void k_keys(const float* __restrict__ cls,
                                               u32* __restrict__ keys,
                                               u32* __restrict__ hist) {
    __shared__ u32 h[H1BINS];
    int t = threadIdx.x;
    h[t] = 0;
    __syncthreads();
    for (int i = blockIdx.x * 1024 + t; i < N_ANCH; i += gridDim.x * 1024) {
        float c0 = cls[3 * i], c1 = cls[3 * i + 1], c2 = cls[3 * i + 2];
        float m = fmaxf(c0, fmaxf(c1, c2));
        float s = 1.0f / (1.0f + expf(-m));
        u32 k = (s >= 0.05f) ? __float_as_uint(s) : 0u;
        keys[i] = k;
        u32 bin = k ? ((k >> 16) - H1BASE + 1u) : 0u;   // valid upper16 in [0x3D4C,0x3F80]
        atomicAdd(&h[bin], 1u);
    }
    __syncthreads();
    u32 c = h[t];
    if (c) atomicAdd(&hist[t], c);
}

// pass-1 scan over 1024 remapped bins: find crossing bucket from the top
__global__ __launch_bounds__(1024) void k_scan1(const u32* __restrict__ hist, u32* scal) {
    __shared__ u32 sh[1024];
    int t = threadIdx.x;
    int b = 1023 - t;                 // descending bins
    u32 s = hist[b];
    sh[t] = s;
    __syncthreads();
    for (int off = 1; off < 1024; off <<= 1) {
        u32 x = sh[t];
        u32 y = (t >= off) ? sh[t - off] : 0u;
        __syncthreads();
        sh[t] = x + y;
        __syncthreads();
    }
    u32 incl = sh[t];
    u32 excl = incl - s;
    if (excl < 4096u && incl >= 4096u) {
        scal[0] = (u32)b;                                   // remapped crossing bin
        scal[1] = excl;                                     // count strictly above bucket
        scal[8] = (b > 0) ? (u32)(b - 1) + H1BASE : 0u;     // actual upper-16 bits
    }
}

__global__ void k_hist2(const u32* __restrict__ keys, u32* __restrict__ hist2,
                        const u32* __restrict__ scal) {
    int i = blockIdx.x * blockDim.x + threadIdx.x;
    if (i >= N_ANCH) return;
    u32 k = keys[i];
    if ((k >> 16) == scal[8]) atomicAdd(&hist2[k & 0xFFFFu], 1u);
}

// pass-2 scan over 65536 lower-16 bins of the crossing bucket
__global__ __launch_bounds__(1024) void k_scan2(const u32* __restrict__ hist, u32* scal) {
    __shared__ u32 sh[1024];
    int t = threadIdx.x;
    int hi = 65535 - t * 64;
    u32 s = 0;
    for (int j = 0; j < 64; ++j) s += hist[hi - j];
    sh[t] = s;
    __syncthreads();
    for (int off = 1; off < 1024; off <<= 1) {
        u32 x = sh[t];
        u32 y = (t >= off) ? sh[t - off] : 0u;
        __syncthreads();
        sh[t] = x + y;
        __syncthreads();
    }
    u32 incl = sh[t];
    u32 excl = incl - s;
    u32 base = scal[1];
    u32 target = 4096u - base;
    if (excl < target && excl + s >= target) {
        u32 cum = excl;
        for (int j = 0; j < 64; ++j) {
            int b = hi - j;
            u32 c = hist[b];
            if (cum + c >= target) {
                u32 T = (scal[8] << 16) | (u32)b;
                u32 cgt = base + cum;
                scal[2] = T; scal[3] = cgt; scal[4] = 4096u - cgt;
                break;
            }
            cum += c;
        }
    }
}

__global__ void k_compact(const u32* __restrict__ keys, u32* scal, u64* __restrict__ sel,
                          u32* __restrict__ eq) {
    int i = blockIdx.x * blockDim.x + threadIdx.x;
    if (i >= N_ANCH) return;
    u32 k = keys[i];
    u32 T = scal[2];
    if (k > T) {
        u32 p = atomicAdd(&scal[5], 1u);
        sel[p] = (((u64)k) << 32) | (u32)(~(u32)i);
    } else if (k == T) {
        u32 p = atomicAdd(&scal[6], 1u);
        if (p < EQCAP) eq[p] = (u32)i;
    }
}

// rank the ==T indices by counting (ascending index); append the keq smallest
__global__ __launch_bounds__(1024) void k_eqrank(const u32* __restrict__ scal,
                                                 const u32* __restrict__ eq,
                                                 u64* __restrict__ sel) {
    __shared__ u32 ch[1024];
    u32 ce = scal[6]; if (ce > EQCAP) ce = EQCAP;
    u32 keq = scal[4], cgt = scal[3], T = scal[2];
    int t = threadIdx.x;
    for (u32 p0 = 0; p0 < ce; p0 += 1024) {
        u32 p = p0 + (u32)t;
        u32 mine = (p < ce) ? eq[p] : 0xFFFFFFFFu;
        u32 rank = 0;
        for (u32 base = 0; base < ce; base += 1024) {
            u32 n = ce - base; if (n > 1024u) n = 1024u;
            __syncthreads();
            if ((u32)t < n) ch[t] = eq[base + t];
            __syncthreads();
            for (u32 j = 0; j < n; ++j) rank += (ch[j] < mine) ? 1u : 0u;
        }
        if (p < ce && rank < keq) sel[cgt + rank] = (((u64)T) << 32) | (u32)(~mine);
    }
}

// rank-by-counting scatter: all 4096 packed keys distinct -> permutation
__global__ __launch_bounds__(256) void k_rank(const u64* __restrict__ sel,
                                              u64* __restrict__ sorted) {
    __shared__ u64 ch[2048];
    int r = blockIdx.x * 256 + threadIdx.x;
    u64 mine = sel[r];
    int rank = 0;
    for (int base = 0; base < KSEL; base += 2048) {
        for (int j = threadIdx.x; j < 2048; j += 256) ch[j] = sel[base + j];
        __syncthreads();
        #pragma unroll 8
        for (int j = 0; j < 2048; ++j) rank += (ch[j] > mine) ? 1 : 0;
        __syncthreads();
    }
    sorted[rank] = mine;   // descending: rank 0 = max key
}

__global__ void k_decode(const u64* __restrict__ sel, const float* __restrict__ boxp,
                         const float* __restrict__ anch, float* __restrict__ boxes7,
                         float4* __restrict__ bb, float* __restrict__ area,
                         float* __restrict__ prescore, u32* __restrict__ preidx) {
    int r = blockIdx.x * blockDim.x + threadIdx.x;
    if (r >= KSEL) return;
    u64 c = sel[r];
    u32 key = (u32)(c >> 32);
    u32 idx = ~((u32)(c & 0xFFFFFFFFull));
    if (key == 0u) idx = 0u;
    const float* a7 = anch + (size_t)idx * 7;
    const float* t7 = boxp + (size_t)idx * 7;
    float xa = a7[0], ya = a7[1], za = a7[2], wa = a7[3], la = a7[4], ha = a7[5], ra = a7[6];
    float xt = t7[0], yt = t7[1], zt = t7[2], wt = t7[3], lt_ = t7[4], ht = t7[5], rt = t7[6];
    za = za + ha * 0.5f;
    float diag = sqrtf(la * la + wa * wa);
    float xg = xt * diag + xa;
    float yg = yt * diag + ya;
    float zg = zt * ha + za;
    float lg = expf(lt_) * la;
    float wg = expf(wt) * wa;
    float hg = expf(ht) * ha;
    float rg = rt + ra;
    zg = zg - hg * 0.5f;
    float* b = boxes7 + (size_t)r * 7;
    b[0] = xg; b[1] = yg; b[2] = zg; b[3] = wg; b[4] = lg; b[5] = hg; b[6] = rg;
    float cc = cosf(rg), ss = sinf(rg);
    float dx = wg * 0.5f, dy = lg * 0.5f;
    const float sxs[4] = {-1.f, -1.f, 1.f, 1.f};
    const float sys[4] = {-1.f, 1.f, 1.f, -1.f};
    float minx = 1e30f, miny = 1e30f, maxx = -1e30f, maxy = -1e30f;
    for (int k = 0; k < 4; ++k) {
        float cx = dx * sxs[k], cy = dy * sys[k];
        float px = cx * cc + cy * ss;
        float py = cx * (-ss) + cy * cc;
        px = px + xg; py = py + yg;
        minx = fminf(minx, px); maxx = fmaxf(maxx, px);
        miny = fminf(miny, py); maxy = fmaxf(maxy, py);
    }
    bb[r] = make_float4(minx, miny, maxx, maxy);
    area[r] = (maxx - minx) * (maxy - miny);
    prescore[r] = (key == 0u) ? -1.0f : __uint_as_float(key);
    preidx[r] = idx;
}

__global__ __launch_bounds__(64) void k_mask(const float4* __restrict__ bb,
                                             const float* __restrict__ area,
                                             u64* __restrict__ mask) {
    int i = blockIdx.y * 64 + threadIdx.x;
    int cb = blockIdx.x;
    __shared__ float4 ob[64];
    __shared__ float oa[64];
    int jg0 = cb * 64;
    ob[threadIdx.x] = bb[jg0 + threadIdx.x];
    oa[threadIdx.x] = area[jg0 + threadIdx.x];
    __syncthreads();
    float4 m = bb[i];
    float ma = area[i];
    u64 bits = 0;
    for (int j = 0; j < 64; ++j) {
        int jg = jg0 + j;
        if (jg == i) continue;
        float4 o = ob[j];
        float ltx = fmaxf(m.x, o.x), lty = fmaxf(m.y, o.y);
        float rbx = fminf(m.z, o.z), rby = fminf(m.w, o.w);
        float w = fmaxf(rbx - ltx, 0.0f), h = fmaxf(rby - lty, 0.0f);
        float inter = w * h;
        float iou = inter / (ma + oa[j] - inter + 1e-8f);
        if (iou > 0.5f) bits |= (1ULL << j);
    }
    mask[(size_t)i * 64 + cb] = bits;
}

__device__ __forceinline__ u64 shfl_u64(u64 v, int src) {
    int lo = __shfl((int)(u32)(v & 0xFFFFFFFFull), src);
    int hi = __shfl((int)(u32)(v >> 32), src);
    return (((u64)(u32)hi) << 32) | (u32)lo;
}

__device__ __forceinline__ int first_avail(u64 avail) {
    u64 ball = __ballot(avail != 0);
    if (ball == 0) return -1;
    int src = (int)__builtin_ctzll(ball);
    u64 w = shfl_u64(avail, src);
    int bit = (int)__builtin_ctzll(w);
    return src * 64 + bit;
}

// one wave; lane l owns bits [l*64, l*64+64) of the availability bitmap.
// 8-deep speculative greedy NMS: pick 8 candidates ignoring mutual suppression,
// fetch their 8 mask rows in parallel, commit in order with an O(1) recheck.
__global__ __launch_bounds__(64) void k_serial(const u64* __restrict__ mask,
                                               const float* __restrict__ prescore,
                                               u32* __restrict__ keep_list, u32* __restrict__ scal) {
    int lane = threadIdx.x;
    u64 avail = 0;
    for (int j = 0; j < 64; ++j)
        if (prescore[(size_t)lane * 64 + j] > 0.0f) avail |= (1ULL << j);
    int cnt = 0;
    for (;;) {
        int cand[8];
        u64 rows[8];
        u64 tmp = avail;
        #pragma unroll
        for (int d = 0; d < 8; ++d) {
            int c = first_avail(tmp);
            cand[d] = c;
            if (c >= 0 && lane == (c >> 6)) tmp &= ~(1ULL << (c & 63));
        }
        if (cand[0] < 0) break;
        #pragma unroll
        for (int d = 0; d < 8; ++d)
            rows[d] = (cand[d] >= 0) ? mask[(size_t)cand[d] * 64 + lane] : 0ULL;
        bool stop = false, restart = false;
        #pragma unroll
        for (int d = 0; d < 8; ++d) {
            if (stop || restart) continue;
            int c = cand[d];
            if (c < 0) continue;
            int ok = __shfl((int)((avail >> (c & 63)) & 1ULL), c >> 6);
            if (!ok) { restart = true; continue; }
            if (lane == 0 && cnt < POST) keep_list[cnt] = (u32)c;
            cnt++;
            avail &= ~rows[d];
            if (lane == (c >> 6)) avail &= ~(1ULL << (c & 63));
            if (cnt >= POST) stop = true;
        }
        if (stop) break;
    }
    if (lane == 0) scal[7] = (u32)(cnt < POST ? cnt : POST);
}

__global__ void k_final(const u32* __restrict__ scal, const u32* __restrict__ keep_list,
                        const float* __restrict__ boxes7, const float* __restrict__ prescore,
                        const u32* __restrict__ preidx, const float* __restrict__ cls,
                        const float* __restrict__ dirp, float* __restrict__ out) {
    int t = blockIdx.x * blockDim.x + threadIdx.x;
    if (t >= POST) return;
    u32 m = scal[7];
    float* ob = out;
    float* os = out + POST * 7;
    float* ol = os + POST;
    float* ov = ol + POST;
    if (t < (int)m) {
        u32 r = keep_list[t];
        u32 i = preidx[r];
        float b[7];
        for (int q = 0; q < 7; ++q) b[q] = boxes7[(size_t)r * 7 + q];
        float d0 = dirp[(size_t)i * 2], d1 = dirp[(size_t)i * 2 + 1];
        int dl = (d1 > d0) ? 1 : 0;
        int pos = (b[6] > 0.0f) ? 1 : 0;
        if (pos ^ dl) b[6] = b[6] + 3.14159265358979323846f;
        for (int q = 0; q < 7; ++q) ob[(size_t)t * 7 + q] = b[q];
        os[t] = prescore[r];
        float c0 = cls[(size_t)i * 3], c1 = cls[(size_t)i * 3 + 1], c2 = cls[(size_t)i * 3 + 2];
        int lab = 0; float best = c0;
        if (c1 > best) { lab = 1; best = c1; }
        if (c2 > best) { lab = 2; }
        ol[t] = (float)lab;
        ov[t] = 1.0f;
    } else {
        for (int q = 0; q < 7; ++q) ob[(size_t)t * 7 + q] = 0.0f;
        os[t] = 0.0f;
        ol[t] = -1.0f;
        ov[t] = 0.0f;
    }
}

extern "C" void kernel_launch(void* const* d_in, const int* in_sizes, int n_in,
                              void* d_out, int out_size, void* d_ws, size_t ws_size,
                              hipStream_t stream) {
    const float* box_preds = (const float*)d_in[0];
    const float* cls_preds = (const float*)d_in[1];
    const float* dir_preds = (const float*)d_in[2];
    const float* anchors   = (const float*)d_in[3];
    float* out = (float*)d_out;

    unsigned char* w = (unsigned char*)d_ws;
    size_t off = 0;
    auto nxt = [&](size_t bytes) -> void* {
        void* p = (void*)(w + off);
        off = (off + bytes + 255) & ~(size_t)255;
        return p;
    };
    u32* keys      = (u32*)nxt((size_t)N_ANCH * 4);
    u32* hist1     = (u32*)nxt(H1BINS * 4);          // contiguous:
    u32* hist2     = (u32*)nxt(65536 * 4);           //   one memset covers
    u32* scal      = (u32*)nxt(64 * 4);              //   hist1+hist2+scal
    u64* sel       = (u64*)nxt((size_t)KSEL * 8);
    u64* sel2      = (u64*)nxt((size_t)KSEL * 8);
    u32* eq        = (u32*)nxt((size_t)EQCAP * 4);
    float* boxes7  = (float*)nxt((size_t)KSEL * 7 * 4);
    float4* bb     = (float4*)nxt((size_t)KSEL * 16);
    float* area    = (float*)nxt((size_t)KSEL * 4);
    float* prescore= (float*)nxt((size_t)KSEL * 4);
    u32* preidx    = (u32*)nxt((size_t)KSEL * 4);
    u64* mask      = (u64*)nxt((size_t)KSEL * 64 * 8);
    u32* keep_list = (u32*)nxt(512 * 4);

    hipMemsetAsync(hist1, 0, (size_t)H1BINS * 4 + (size_t)65536 * 4 + 256, stream);

    int blocks = (N_ANCH + 255) / 256;
    k_keys<<<64, 1024, 0, stream>>>(cls_preds, keys, hist1);
    k_scan1<<<1, 1024, 0, stream>>>(hist1, scal);
    k_hist2<<<blocks, 256, 0, stream>>>(keys, hist2, scal);
    k_scan2<<<1, 1024, 0, stream>>>(hist2, scal);
    k_compact<<<blocks, 256, 0, stream>>>(keys, scal, sel, eq);
    k_eqrank<<<1, 1024, 0, stream>>>(scal, eq, sel);
    k_rank<<<KSEL / 256, 256, 0, stream>>>(sel, sel2);
    k_decode<<<KSEL / 256, 256, 0, stream>>>(sel2, box_preds, anchors, boxes7, bb, area, prescore, preidx);
    dim3 mg(64, 64);
    k_mask<<<mg, 64, 0, stream>>>(bb, area, mask);
    k_serial<<<1, 64, 0, stream>>>(mask, prescore, keep_list, scal);
    k_final<<<2, 256, 0, stream>>>(scal, keep_list, boxes7, prescore, preidx, cls_preds, dir_preds, out);
}

// Round 4
// 237.476 us; speedup vs baseline: 5.0803x; 1.2294x over previous
//
#include <hip/hip_runtime.h>

#pragma clang fp contract(off)

#define N_ANCH 321408
#define KSEL 4096
#define POST 300
#define H1BINS 1024
#define H1BASE 0x3D40u   // remap: bin = (k>>16) - H1BASE + 1 ; bin 0 = invalid (k==0)
#define CANDCAP 16384

typedef unsigned int u32;
typedef unsigned long long u64;

// ---------------- scoring + coarse histogram (LDS-privatized) ----------------
__global__ __launch_bounds__(1024) void k_keys(const float* __restrict__ cls,
                                               u32* __restrict__ keys,
                                               u32* __restrict__ hist) {
    __shared__ u32 h[H1BINS];
    int t = threadIdx.x;
    h[t] = 0;
    __syncthreads();
    for (int i = blockIdx.x * 1024 + t; i < N_ANCH; i += gridDim.x * 1024) {
        float c0 = cls[3 * i], c1 = cls[3 * i + 1], c2 = cls[3 * i + 2];
        float m = fmaxf(c0, fmaxf(c1, c2));
        float s = 1.0f / (1.0f + expf(-m));
        u32 k = (s >= 0.05f) ? __float_as_uint(s) : 0u;
        keys[i] = k;
        u32 bin = k ? ((k >> 16) - H1BASE + 1u) : 0u;
        atomicAdd(&h[bin], 1u);
    }
    __syncthreads();
    u32 c = h[t];
    if (c) atomicAdd(&hist[t], c);
}

// scan 1024 coarse bins from the top: crossing bin + total valid count
__global__ __launch_bounds__(1024) void k_scan1(const u32* __restrict__ hist, u32* scal) {
    __shared__ u32 sh[1024];
    int t = threadIdx.x;
    int b = 1023 - t;                 // descending bins
    u32 s = hist[b];
    sh[t] = s;
    __syncthreads();
    for (int off = 1; off < 1024; off <<= 1) {
        u32 x = sh[t];
        u32 y = (t >= off) ? sh[t - off] : 0u;
        __syncthreads();
        sh[t] = x + y;
        __syncthreads();
    }
    u32 incl = sh[t];
    u32 excl = incl - s;
    if (excl < 4096u && incl >= 4096u) {
        scal[8] = (b > 0) ? (u32)(b - 1) + H1BASE : 0u;   // actual upper-16 of crossing bin
    }
    if (t == 1023) scal[9] = incl - s;                    // total valid (all bins minus bin 0)
}

// all candidates in bins >= crossing bin, packed (key<<32)|~idx
__global__ void k_compact(const u32* __restrict__ keys, u32* scal, u64* __restrict__ cand) {
    int i = blockIdx.x * blockDim.x + threadIdx.x;
    if (i >= N_ANCH) return;
    u32 k = keys[i];
    if (k && (k >> 16) >= scal[8]) {
        u32 p = atomicAdd(&scal[5], 1u);
        if (p < CANDCAP) cand[p] = (((u64)k) << 32) | (u32)(~(u32)i);
    }
}

// exact top-4096 by counting rank; full u64 compare = score desc, idx asc
__global__ __launch_bounds__(256) void k_rank(const u32* __restrict__ scal,
                                              const u64* __restrict__ cand,
                                              u64* __restrict__ sorted) {
    __shared__ u64 ch[2048];
    u32 nc = scal[5]; if (nc > CANDCAP) nc = CANDCAP;
    u32 t = blockIdx.x * 256 + threadIdx.x;
    u64 mine = (t < nc) ? cand[t] : 0ull;
    u32 rank = 0;
    for (u32 base = 0; base < nc; base += 2048) {
        for (u32 j = threadIdx.x; j < 2048; j += 256)
            ch[j] = (base + j < nc) ? cand[base + j] : 0ull;
        __syncthreads();
        #pragma unroll 8
        for (int j = 0; j < 2048; ++j) rank += (ch[j] > mine) ? 1u : 0u;
        __syncthreads();
    }
    if (t < nc && rank < (u32)KSEL) sorted[rank] = mine;
}

// ---------------- decode helpers (expressions identical to round-3 k_decode) ----------
__device__ __forceinline__ void decode_box(u64 cpack, const float* __restrict__ boxp,
                                           const float* __restrict__ anch, float b[7]) {
    u32 key = (u32)(cpack >> 32);
    u32 idx = ~((u32)(cpack & 0xFFFFFFFFull));
    if (key == 0u) idx = 0u;
    const float* a7 = anch + (size_t)idx * 7;
    const float* t7 = boxp + (size_t)idx * 7;
    float xa = a7[0], ya = a7[1], za = a7[2], wa = a7[3], la = a7[4], ha = a7[5], ra = a7[6];
    float xt = t7[0], yt = t7[1], zt = t7[2], wt = t7[3], lt_ = t7[4], ht = t7[5], rt = t7[6];
    za = za + ha * 0.5f;
    float diag = sqrtf(la * la + wa * wa);
    float xg = xt * diag + xa;
    float yg = yt * diag + ya;
    float zg = zt * ha + za;
    float lg = expf(lt_) * la;
    float wg = expf(wt) * wa;
    float hg = expf(ht) * ha;
    float rg = rt + ra;
    zg = zg - hg * 0.5f;
    b[0] = xg; b[1] = yg; b[2] = zg; b[3] = wg; b[4] = lg; b[5] = hg; b[6] = rg;
}

__device__ __forceinline__ float4 standup_box(const float b[7], float* areao) {
    float xg = b[0], yg = b[1], wg = b[3], lg = b[4], rg = b[6];
    float cc = cosf(rg), ss = sinf(rg);
    float dx = wg * 0.5f, dy = lg * 0.5f;
    const float sxs[4] = {-1.f, -1.f, 1.f, 1.f};
    const float sys[4] = {-1.f, 1.f, 1.f, -1.f};
    float minx = 1e30f, miny = 1e30f, maxx = -1e30f, maxy = -1e30f;
    #pragma unroll
    for (int k = 0; k < 4; ++k) {
        float cx = dx * sxs[k], cy = dy * sys[k];
        float px = cx * cc + cy * ss;
        float py = cx * (-ss) + cy * cc;
        px = px + xg; py = py + yg;
        minx = fminf(minx, px); maxx = fmaxf(maxx, px);
        miny = fminf(miny, py); maxy = fmaxf(maxy, py);
    }
    *areao = (maxx - minx) * (maxy - miny);
    return make_float4(minx, miny, maxx, maxy);
}

// fused decode + standup + 64x64 IoU mask tile
__global__ __launch_bounds__(64) void k_maskdec(const u64* __restrict__ sel2,
                                                const float* __restrict__ boxp,
                                                const float* __restrict__ anch,
                                                u64* __restrict__ mask) {
    __shared__ float4 ob[64];
    __shared__ float oa[64];
    int t = threadIdx.x;
    int i = blockIdx.y * 64 + t;
    int cb = blockIdx.x;
    int jg0 = cb * 64;
    float bc[7];
    decode_box(sel2[jg0 + t], boxp, anch, bc);
    float ac;
    float4 c4 = standup_box(bc, &ac);
    ob[t] = c4; oa[t] = ac;
    float br[7];
    decode_box(sel2[i], boxp, anch, br);
    float ma;
    float4 m4 = standup_box(br, &ma);
    __syncthreads();
    u64 bits = 0;
    for (int j = 0; j < 64; ++j) {
        int jg = jg0 + j;
        if (jg == i) continue;
        float4 o = ob[j];
        float ltx = fmaxf(m4.x, o.x), lty = fmaxf(m4.y, o.y);
        float rbx = fminf(m4.z, o.z), rby = fminf(m4.w, o.w);
        float w = fmaxf(rbx - ltx, 0.0f), h = fmaxf(rby - lty, 0.0f);
        float inter = w * h;
        float iou = inter / (ma + oa[j] - inter + 1e-8f);
        if (iou > 0.5f) bits |= (1ULL << j);
    }
    mask[(size_t)i * 64 + cb] = bits;
}

__device__ __forceinline__ u64 shfl_u64(u64 v, int src) {
    int lo = __shfl((int)(u32)(v & 0xFFFFFFFFull), src);
    int hi = __shfl((int)(u32)(v >> 32), src);
    return (((u64)(u32)hi) << 32) | (u32)lo;
}

// one wave; lane l owns bits [l*64, l*64+64) of the availability bitmap.
// Window-16 greedy: the 16 lowest available ranks are selected in ONE prefix-sum
// chain; within-window suppression is exact (consecutive available ranks), so the
// greedy over the 16x16 matrix needs no cross-lane chain and no restarts.
__global__ __launch_bounds__(64) void k_serial(const u64* __restrict__ mask,
                                               u32* __restrict__ keep_list,
                                               u32* __restrict__ scal) {
    int lane = threadIdx.x;
    u32 nvt = scal[9];
    u32 nv = (nvt < (u32)KSEL) ? nvt : (u32)KSEL;
    int lo = lane * 64;
    u64 avail;
    if ((int)nv >= lo + 64) avail = ~0ull;
    else if ((int)nv <= lo) avail = 0ull;
    else avail = (((u64)1) << (nv - lo)) - 1ull;

    __shared__ int ls_cand[16];
    __shared__ u32 ls_m[16];
    int cnt = 0;
    for (;;) {
        // --- select first 16 available ranks ---
        u32 pc = (u32)__popcll(avail);
        u32 pre = pc;
        #pragma unroll
        for (int off = 1; off < 64; off <<= 1) {
            u32 y = __shfl_up(pre, (unsigned)off);
            if (lane >= off) pre += y;
        }
        u32 excl = pre - pc;
        if (lane < 16) { ls_cand[lane] = -1; ls_m[lane] = 0u; }
        __syncthreads();
        if (pc && excl < 16u) {
            u64 a = avail;
            u32 o = excl;
            while (a && o < 16u) {
                int b = (int)__builtin_ctzll(a);
                a &= a - 1;
                ls_cand[o++] = lo + b;
            }
        }
        __syncthreads();
        int c[16];
        #pragma unroll
        for (int j = 0; j < 16; ++j) c[j] = ls_cand[j];
        if (c[0] < 0) break;
        // --- fetch 16 rows in parallel ---
        u64 rows[16];
        #pragma unroll
        for (int j = 0; j < 16; ++j)
            rows[j] = (c[j] >= 0) ? mask[(size_t)c[j] * 64 + lane] : 0ull;
        // --- lane j<16 gathers its candidate's bit from every row (pipelined bpermutes)
        int src = (lane < 16 && c[lane] >= 0) ? (c[lane] >> 6) : 0;
        int sh  = (lane < 16 && c[lane] >= 0) ? (c[lane] & 63) : 0;
        u32 m = 0;
        #pragma unroll
        for (int jp = 0; jp < 16; ++jp) {
            u64 v = shfl_u64(rows[jp], src);
            m |= (u32)((v >> sh) & 1ull) << jp;
        }
        if (lane < 16 && c[lane] >= 0) ls_m[lane] = m;
        __syncthreads();
        u32 mm[16];
        #pragma unroll
        for (int j = 0; j < 16; ++j) mm[j] = ls_m[j];
        // --- branchless scalar greedy, replicated on all lanes ---
        u32 committed = 0;
        bool stop = false;
        #pragma unroll
        for (int j = 0; j < 16; ++j) {
            if (stop) continue;
            if (c[j] < 0) continue;
            if (mm[j] & committed) continue;     // suppressed by earlier commit in window
            if (lane == 0 && cnt < POST) keep_list[cnt] = (u32)c[j];
            committed |= (1u << j);
            cnt++;
            if (cnt >= POST) stop = true;
        }
        // --- apply committed rows to the global availability bitmap ---
        #pragma unroll
        for (int j = 0; j < 16; ++j) {
            if ((committed >> j) & 1u) {
                avail &= ~rows[j];
                if (lane == (c[j] >> 6)) avail &= ~(((u64)1) << (c[j] & 63));
            }
        }
        if (stop) break;
    }
    if (lane == 0) scal[7] = (u32)(cnt < POST ? cnt : POST);
}

__global__ void k_final(const u32* __restrict__ scal, const u32* __restrict__ keep_list,
                        const u64* __restrict__ sel2, const float* __restrict__ boxp,
                        const float* __restrict__ anch, const float* __restrict__ cls,
                        const float* __restrict__ dirp, float* __restrict__ out) {
    int t = blockIdx.x * blockDim.x + threadIdx.x;
    if (t >= POST) return;
    u32 m = scal[7];
    float* ob = out;
    float* os = out + POST * 7;
    float* ol = os + POST;
    float* ov = ol + POST;
    if (t < (int)m) {
        u32 r = keep_list[t];
        u64 cp = sel2[r];
        u32 key = (u32)(cp >> 32);
        u32 i = ~((u32)(cp & 0xFFFFFFFFull));
        float b[7];
        decode_box(cp, boxp, anch, b);
        float d0 = dirp[(size_t)i * 2], d1 = dirp[(size_t)i * 2 + 1];
        int dl = (d1 > d0) ? 1 : 0;
        int pos = (b[6] > 0.0f) ? 1 : 0;
        if (pos ^ dl) b[6] = b[6] + 3.14159265358979323846f;
        for (int q = 0; q < 7; ++q) ob[(size_t)t * 7 + q] = b[q];
        os[t] = __uint_as_float(key);
        float s0 = 1.0f / (1.0f + expf(-cls[(size_t)i * 3]));
        float s1 = 1.0f / (1.0f + expf(-cls[(size_t)i * 3 + 1]));
        float s2 = 1.0f / (1.0f + expf(-cls[(size_t)i * 3 + 2]));
        int lab = 0; float best = s0;
        if (s1 > best) { lab = 1; best = s1; }
        if (s2 > best) { lab = 2; }
        ol[t] = (float)lab;
        ov[t] = 1.0f;
    } else {
        for (int q = 0; q < 7; ++q) ob[(size_t)t * 7 + q] = 0.0f;
        os[t] = 0.0f;
        ol[t] = -1.0f;
        ov[t] = 0.0f;
    }
}

extern "C" void kernel_launch(void* const* d_in, const int* in_sizes, int n_in,
                              void* d_out, int out_size, void* d_ws, size_t ws_size,
                              hipStream_t stream) {
    const float* box_preds = (const float*)d_in[0];
    const float* cls_preds = (const float*)d_in[1];
    const float* dir_preds = (const float*)d_in[2];
    const float* anchors   = (const float*)d_in[3];
    float* out = (float*)d_out;

    unsigned char* w = (unsigned char*)d_ws;
    size_t off = 0;
    auto nxt = [&](size_t bytes) -> void* {
        void* p = (void*)(w + off);
        off = (off + bytes + 255) & ~(size_t)255;
        return p;
    };
    // memset region: hist1 | scal | sel2 (contiguous)
    u32* hist1     = (u32*)nxt(H1BINS * 4);          // 4096 B
    u32* scal      = (u32*)nxt(64 * 4);              // 256 B
    u64* sel2      = (u64*)nxt((size_t)KSEL * 8);    // 32768 B
    u64* cand      = (u64*)nxt((size_t)CANDCAP * 8);
    u64* mask      = (u64*)nxt((size_t)KSEL * 64 * 8);
    u32* keep_list = (u32*)nxt(512 * 4);
    u32* keys      = (u32*)nxt((size_t)N_ANCH * 4);

    hipMemsetAsync(hist1, 0, (size_t)H1BINS * 4 + 256 + (size_t)KSEL * 8, stream);

    int blocks = (N_ANCH + 255) / 256;
    k_keys<<<64, 1024, 0, stream>>>(cls_preds, keys, hist1);
    k_scan1<<<1, 1024, 0, stream>>>(hist1, scal);
    k_compact<<<blocks, 256, 0, stream>>>(keys, scal, cand);
    k_rank<<<CANDCAP / 256, 256, 0, stream>>>(scal, cand, sel2);
    dim3 mg(64, 64);
    k_maskdec<<<mg, 64, 0, stream>>>(sel2, box_preds, anchors, mask);
    k_serial<<<1, 64, 0, stream>>>(mask, keep_list, scal);
    k_final<<<2, 256, 0, stream>>>(scal, keep_list, sel2, box_preds, anchors, cls_preds, dir_preds, out);
}

// Round 5
// 161.481 us; speedup vs baseline: 7.4711x; 1.4706x over previous
//
#include <hip/hip_runtime.h>

#pragma clang fp contract(off)

#define N_ANCH 321408
#define KSEL 4096
#define POST 300
#define H1BINS 1024
#define H1BASE 0x3D40u   // remap: bin = (k>>16) - H1BASE + 1 ; bin 0 = invalid (k==0)
#define CANDCAP 16384

typedef unsigned int u32;
typedef unsigned long long u64;

// ---------------- scoring + coarse histogram (LDS-privatized) ----------------
__global__ __launch_bounds__(1024) void k_keys(const float* __restrict__ cls,
                                               u32* __restrict__ keys,
                                               u32* __restrict__ hist) {
    __shared__ u32 h[H1BINS];
    int t = threadIdx.x;
    h[t] = 0;
    __syncthreads();
    for (int i = blockIdx.x * 1024 + t; i < N_ANCH; i += gridDim.x * 1024) {
        float c0 = cls[3 * i], c1 = cls[3 * i + 1], c2 = cls[3 * i + 2];
        float m = fmaxf(c0, fmaxf(c1, c2));
        float s = 1.0f / (1.0f + expf(-m));
        u32 k = (s >= 0.05f) ? __float_as_uint(s) : 0u;
        keys[i] = k;
        u32 bin = k ? ((k >> 16) - H1BASE + 1u) : 0u;
        atomicAdd(&h[bin], 1u);
    }
    __syncthreads();
    u32 c = h[t];
    if (c) atomicAdd(&hist[t], c);
}

// scan 1024 coarse bins from the top: crossing bin + total valid count
__global__ __launch_bounds__(1024) void k_scan1(const u32* __restrict__ hist, u32* scal) {
    __shared__ u32 sh[1024];
    int t = threadIdx.x;
    int b = 1023 - t;                 // descending bins
    u32 s = hist[b];
    sh[t] = s;
    __syncthreads();
    for (int off = 1; off < 1024; off <<= 1) {
        u32 x = sh[t];
        u32 y = (t >= off) ? sh[t - off] : 0u;
        __syncthreads();
        sh[t] = x + y;
        __syncthreads();
    }
    u32 incl = sh[t];
    u32 excl = incl - s;
    if (excl < 4096u && incl >= 4096u) {
        scal[8] = (b > 0) ? (u32)(b - 1) + H1BASE : 0u;   // actual upper-16 of crossing bin
    }
    if (t == 1023) scal[9] = incl - s;                    // total valid (all bins minus bin 0)
}

// all candidates in bins >= crossing bin, packed (key<<32)|~idx
__global__ void k_compact(const u32* __restrict__ keys, u32* scal, u64* __restrict__ cand) {
    int i = blockIdx.x * blockDim.x + threadIdx.x;
    if (i >= N_ANCH) return;
    u32 k = keys[i];
    if (k && (k >> 16) >= scal[8]) {
        u32 p = atomicAdd(&scal[5], 1u);
        if (p < CANDCAP) cand[p] = (((u64)k) << 32) | (u32)(~(u32)i);
    }
}

// 2D partial rank-by-counting: block (x,y) ranks candidates [x*256,x*256+256)
// against chunk [y*512, y*512+512); partial ranks accumulate via atomicAdd.
__global__ __launch_bounds__(256) void k_rankpart(const u32* __restrict__ scal,
                                                  const u64* __restrict__ cand,
                                                  u32* __restrict__ rank) {
    __shared__ u64 ch[512];
    u32 nc = scal[5]; if (nc > CANDCAP) nc = CANDCAP;
    u32 cb = blockIdx.x * 256u;
    u32 jb = blockIdx.y * 512u;
    if (cb >= nc || jb >= nc) return;
    u32 t = threadIdx.x;
    for (u32 j = t; j < 512u; j += 256u)
        ch[j] = (jb + j < nc) ? cand[jb + j] : 0ull;   // 0 is never > any valid key
    __syncthreads();
    u32 me = cb + t;
    u64 mine = (me < nc) ? cand[me] : ~0ull;           // sentinel: nothing > ~0
    u32 r = 0;
    #pragma unroll 8
    for (int j = 0; j < 512; ++j) r += (ch[j] > mine) ? 1u : 0u;
    if (me < nc && r) atomicAdd(&rank[me], r);
}

// scatter into sorted order (rank 0 = max); sel2 pre-zeroed for padding
__global__ void k_scatter(const u32* __restrict__ scal, const u64* __restrict__ cand,
                          const u32* __restrict__ rank, u64* __restrict__ sorted) {
    u32 nc = scal[5]; if (nc > CANDCAP) nc = CANDCAP;
    u32 t = blockIdx.x * 256u + threadIdx.x;
    if (t < nc) {
        u32 r = rank[t];
        if (r < (u32)KSEL) sorted[r] = cand[t];
    }
}

// ---------------- decode helpers ----------
__device__ __forceinline__ void decode_box(u64 cpack, const float* __restrict__ boxp,
                                           const float* __restrict__ anch, float b[7]) {
    u32 key = (u32)(cpack >> 32);
    u32 idx = ~((u32)(cpack & 0xFFFFFFFFull));
    if (key == 0u) idx = 0u;
    const float* a7 = anch + (size_t)idx * 7;
    const float* t7 = boxp + (size_t)idx * 7;
    float xa = a7[0], ya = a7[1], za = a7[2], wa = a7[3], la = a7[4], ha = a7[5], ra = a7[6];
    float xt = t7[0], yt = t7[1], zt = t7[2], wt = t7[3], lt_ = t7[4], ht = t7[5], rt = t7[6];
    za = za + ha * 0.5f;
    float diag = sqrtf(la * la + wa * wa);
    float xg = xt * diag + xa;
    float yg = yt * diag + ya;
    float zg = zt * ha + za;
    float lg = expf(lt_) * la;
    float wg = expf(wt) * wa;
    float hg = expf(ht) * ha;
    float rg = rt + ra;
    zg = zg - hg * 0.5f;
    b[0] = xg; b[1] = yg; b[2] = zg; b[3] = wg; b[4] = lg; b[5] = hg; b[6] = rg;
}

__device__ __forceinline__ float4 standup_box(const float b[7], float* areao) {
    float xg = b[0], yg = b[1], wg = b[3], lg = b[4], rg = b[6];
    float cc = cosf(rg), ss = sinf(rg);
    float dx = wg * 0.5f, dy = lg * 0.5f;
    const float sxs[4] = {-1.f, -1.f, 1.f, 1.f};
    const float sys[4] = {-1.f, 1.f, 1.f, -1.f};
    float minx = 1e30f, miny = 1e30f, maxx = -1e30f, maxy = -1e30f;
    #pragma unroll
    for (int k = 0; k < 4; ++k) {
        float cx = dx * sxs[k], cy = dy * sys[k];
        float px = cx * cc + cy * ss;
        float py = cx * (-ss) + cy * cc;
        px = px + xg; py = py + yg;
        minx = fminf(minx, px); maxx = fmaxf(maxx, px);
        miny = fminf(miny, py); maxy = fmaxf(maxy, py);
    }
    *areao = (maxx - minx) * (maxy - miny);
    return make_float4(minx, miny, maxx, maxy);
}

// fused decode + standup + 64x64 IoU mask tile
__global__ __launch_bounds__(64) void k_maskdec(const u64* __restrict__ sel2,
                                                const float* __restrict__ boxp,
                                                const float* __restrict__ anch,
                                                u64* __restrict__ mask) {
    __shared__ float4 ob[64];
    __shared__ float oa[64];
    int t = threadIdx.x;
    int i = blockIdx.y * 64 + t;
    int cb = blockIdx.x;
    int jg0 = cb * 64;
    float bc[7];
    decode_box(sel2[jg0 + t], boxp, anch, bc);
    float ac;
    float4 c4 = standup_box(bc, &ac);
    ob[t] = c4; oa[t] = ac;
    float br[7];
    decode_box(sel2[i], boxp, anch, br);
    float ma;
    float4 m4 = standup_box(br, &ma);
    __syncthreads();
    u64 bits = 0;
    for (int j = 0; j < 64; ++j) {
        int jg = jg0 + j;
        if (jg == i) continue;
        float4 o = ob[j];
        float ltx = fmaxf(m4.x, o.x), lty = fmaxf(m4.y, o.y);
        float rbx = fminf(m4.z, o.z), rby = fminf(m4.w, o.w);
        float w = fmaxf(rbx - ltx, 0.0f), h = fmaxf(rby - lty, 0.0f);
        float inter = w * h;
        float iou = inter / (ma + oa[j] - inter + 1e-8f);
        if (iou > 0.5f) bits |= (1ULL << j);
    }
    mask[(size_t)i * 64 + cb] = bits;
}

__device__ __forceinline__ u64 shfl_u64(u64 v, int src) {
    int lo = __shfl((int)(u32)(v & 0xFFFFFFFFull), src);
    int hi = __shfl((int)(u32)(v >> 32), src);
    return (((u64)(u32)hi) << 32) | (u32)lo;
}

// one wave; lane l owns bits [l*64, l*64+64) of the availability bitmap.
// Window-16 greedy: the 16 lowest available ranks selected via one prefix-sum;
// within-window suppression via 16x16 matrix; no restarts.
__global__ __launch_bounds__(64) void k_serial(const u64* __restrict__ mask,
                                               u32* __restrict__ keep_list,
                                               u32* __restrict__ scal) {
    int lane = threadIdx.x;
    u32 nvt = scal[9];
    u32 nv = (nvt < (u32)KSEL) ? nvt : (u32)KSEL;
    int lo = lane * 64;
    u64 avail;
    if ((int)nv >= lo + 64) avail = ~0ull;
    else if ((int)nv <= lo) avail = 0ull;
    else avail = (((u64)1) << (nv - lo)) - 1ull;

    __shared__ int ls_cand[16];
    __shared__ u32 ls_m[16];
    int cnt = 0;
    for (;;) {
        u32 pc = (u32)__popcll(avail);
        u32 pre = pc;
        #pragma unroll
        for (int off = 1; off < 64; off <<= 1) {
            u32 y = __shfl_up(pre, (unsigned)off);
            if (lane >= off) pre += y;
        }
        u32 excl = pre - pc;
        if (lane < 16) { ls_cand[lane] = -1; ls_m[lane] = 0u; }
        __syncthreads();
        if (pc && excl < 16u) {
            u64 a = avail;
            u32 o = excl;
            while (a && o < 16u) {
                int b = (int)__builtin_ctzll(a);
                a &= a - 1;
                ls_cand[o++] = lo + b;
            }
        }
        __syncthreads();
        int c[16];
        #pragma unroll
        for (int j = 0; j < 16; ++j) c[j] = ls_cand[j];
        if (c[0] < 0) break;
        u64 rows[16];
        #pragma unroll
        for (int j = 0; j < 16; ++j)
            rows[j] = (c[j] >= 0) ? mask[(size_t)c[j] * 64 + lane] : 0ull;
        int src = (lane < 16 && c[lane] >= 0) ? (c[lane] >> 6) : 0;
        int sh  = (lane < 16 && c[lane] >= 0) ? (c[lane] & 63) : 0;
        u32 m = 0;
        #pragma unroll
        for (int jp = 0; jp < 16; ++jp) {
            u64 v = shfl_u64(rows[jp], src);
            m |= (u32)((v >> sh) & 1ull) << jp;
        }
        if (lane < 16 && c[lane] >= 0) ls_m[lane] = m;
        __syncthreads();
        u32 mm[16];
        #pragma unroll
        for (int j = 0; j < 16; ++j) mm[j] = ls_m[j];
        u32 committed = 0;
        bool stop = false;
        #pragma unroll
        for (int j = 0; j < 16; ++j) {
            if (stop) continue;
            if (c[j] < 0) continue;
            if (mm[j] & committed) continue;
            if (lane == 0 && cnt < POST) keep_list[cnt] = (u32)c[j];
            committed |= (1u << j);
            cnt++;
            if (cnt >= POST) stop = true;
        }
        #pragma unroll
        for (int j = 0; j < 16; ++j) {
            if ((committed >> j) & 1u) {
                avail &= ~rows[j];
                if (lane == (c[j] >> 6)) avail &= ~(((u64)1) << (c[j] & 63));
            }
        }
        if (stop) break;
    }
    if (lane == 0) scal[7] = (u32)(cnt < POST ? cnt : POST);
}

__global__ void k_final(const u32* __restrict__ scal, const u32* __restrict__ keep_list,
                        const u64* __restrict__ sel2, const float* __restrict__ boxp,
                        const float* __restrict__ anch, const float* __restrict__ cls,
                        const float* __restrict__ dirp, float* __restrict__ out) {
    int t = blockIdx.x * blockDim.x + threadIdx.x;
    if (t >= POST) return;
    u32 m = scal[7];
    float* ob = out;
    float* os = out + POST * 7;
    float* ol = os + POST;
    float* ov = ol + POST;
    if (t < (int)m) {
        u32 r = keep_list[t];
        u64 cp = sel2[r];
        u32 key = (u32)(cp >> 32);
        u32 i = ~((u32)(cp & 0xFFFFFFFFull));
        float b[7];
        decode_box(cp, boxp, anch, b);
        float d0 = dirp[(size_t)i * 2], d1 = dirp[(size_t)i * 2 + 1];
        int dl = (d1 > d0) ? 1 : 0;
        int pos = (b[6] > 0.0f) ? 1 : 0;
        if (pos ^ dl) b[6] = b[6] + 3.14159265358979323846f;
        for (int q = 0; q < 7; ++q) ob[(size_t)t * 7 + q] = b[q];
        os[t] = __uint_as_float(key);
        float s0 = 1.0f / (1.0f + expf(-cls[(size_t)i * 3]));
        float s1 = 1.0f / (1.0f + expf(-cls[(size_t)i * 3 + 1]));
        float s2 = 1.0f / (1.0f + expf(-cls[(size_t)i * 3 + 2]));
        int lab = 0; float best = s0;
        if (s1 > best) { lab = 1; best = s1; }
        if (s2 > best) { lab = 2; }
        ol[t] = (float)lab;
        ov[t] = 1.0f;
    } else {
        for (int q = 0; q < 7; ++q) ob[(size_t)t * 7 + q] = 0.0f;
        os[t] = 0.0f;
        ol[t] = -1.0f;
        ov[t] = 0.0f;
    }
}

extern "C" void kernel_launch(void* const* d_in, const int* in_sizes, int n_in,
                              void* d_out, int out_size, void* d_ws, size_t ws_size,
                              hipStream_t stream) {
    const float* box_preds = (const float*)d_in[0];
    const float* cls_preds = (const float*)d_in[1];
    const float* dir_preds = (const float*)d_in[2];
    const float* anchors   = (const float*)d_in[3];
    float* out = (float*)d_out;

    unsigned char* w = (unsigned char*)d_ws;
    size_t off = 0;
    auto nxt = [&](size_t bytes) -> void* {
        void* p = (void*)(w + off);
        off = (off + bytes + 255) & ~(size_t)255;
        return p;
    };
    // memset region (contiguous): hist1 | scal | sel2 | rank
    u32* hist1     = (u32*)nxt(H1BINS * 4);            //  4096 B
    u32* scal      = (u32*)nxt(64 * 4);                //   256 B
    u64* sel2      = (u64*)nxt((size_t)KSEL * 8);      // 32768 B
    u32* rank      = (u32*)nxt((size_t)CANDCAP * 4);   // 65536 B
    u64* cand      = (u64*)nxt((size_t)CANDCAP * 8);
    u64* mask      = (u64*)nxt((size_t)KSEL * 64 * 8);
    u32* keep_list = (u32*)nxt(512 * 4);
    u32* keys      = (u32*)nxt((size_t)N_ANCH * 4);

    hipMemsetAsync(hist1, 0,
                   (size_t)H1BINS * 4 + 256 + (size_t)KSEL * 8 + (size_t)CANDCAP * 4,
                   stream);

    int blocks = (N_ANCH + 255) / 256;
    k_keys<<<64, 1024, 0, stream>>>(cls_preds, keys, hist1);
    k_scan1<<<1, 1024, 0, stream>>>(hist1, scal);
    k_compact<<<blocks, 256, 0, stream>>>(keys, scal, cand);
    dim3 rg(CANDCAP / 256, CANDCAP / 512);
    k_rankpart<<<rg, 256, 0, stream>>>(scal, cand, rank);
    k_scatter<<<CANDCAP / 256, 256, 0, stream>>>(scal, cand, rank, sel2);
    dim3 mg(64, 64);
    k_maskdec<<<mg, 64, 0, stream>>>(sel2, box_preds, anchors, mask);
    k_serial<<<1, 64, 0, stream>>>(mask, keep_list, scal);
    k_final<<<2, 256, 0, stream>>>(scal, keep_list, sel2, box_preds, anchors, cls_preds, dir_preds, out);
}